// Round 2
// baseline (522.533 us; speedup 1.0000x reference)
//
#include <hip/hip_runtime.h>
#include <hip/hip_bf16.h>

typedef __attribute__((ext_vector_type(8))) short short8;
typedef __attribute__((ext_vector_type(4))) float f32x4;

constexpr int T    = 60;    // driven timesteps
constexpr int C    = 128;   // channels == hidden
constexpr int NPIX = 4096;  // samples
constexpr int H    = 128;
constexpr int GP   = 5;
constexpr int EXTRA = T - GP - 1;   // 54 autoregressive steps
constexpr int TT    = T + EXTRA;    // 114 total outputs
constexpr int LS    = 136;          // bf16 elems/row: 272 B, 16B-aligned

__device__ __forceinline__ unsigned short f2bf(float f) {
  unsigned u = __float_as_uint(f);
  u += 0x7FFF + ((u >> 16) & 1);   // RNE
  return (unsigned short)(u >> 16);
}
__device__ __forceinline__ float bf2f(unsigned short s) {
  return __uint_as_float(((unsigned)s) << 16);
}
__device__ __forceinline__ float fast_sigmoid(float x) {
  float e = __builtin_amdgcn_exp2f(-1.44269504f * x);
  return __builtin_amdgcn_rcpf(1.0f + e);
}
__device__ __forceinline__ float fast_tanh(float x) {
  float e = __builtin_amdgcn_exp2f(2.88539008f * x);   // exp(2x)
  return 1.0f - 2.0f * __builtin_amdgcn_rcpf(1.0f + e);
}

// One WG owns 16 samples, runs all 114 steps. 8 waves; wave w owns gate
// columns {nt*128 + 16w .. +15}. Weights live in VGPRs as bf16 B-frags.
// Double-buffered LDS h/x -> ONE barrier per step; out-stores for step t-1
// issued at top of step t so the vmcnt(0)-before-barrier drain overlaps the
// whole step's compute.
__global__ __launch_bounds__(512, 2) void lstm_persistent(
    const float* __restrict__ img,   // [T][C][NPIX]
    const float* __restrict__ wih,   // [4H][C]
    const float* __restrict__ whh,   // [4H][H]
    const float* __restrict__ bih,
    const float* __restrict__ bhh,
    float* __restrict__ out)         // [NPIX][TT][H]
{
  __shared__ __align__(16) unsigned short xs[2][16 * LS];
  __shared__ __align__(16) unsigned short hs[2][16 * LS];

  const int tid  = threadIdx.x;
  const int lane = tid & 63;
  const int w    = tid >> 6;      // wave 0..7
  const int l15  = lane & 15;
  const int quad = lane >> 4;     // 0..3
  const int n0   = blockIdx.x * 16;
  const int hid  = w * 16 + l15;  // hidden column this lane owns

  // ---- weight B-fragments: lane holds B[k=quad*8+j][n=l15] = W[col][k] ----
  short8 fih[4][4], fhh[4][4];
  float bias[4];
  #pragma unroll
  for (int nt = 0; nt < 4; ++nt) {
    const int col = nt * 128 + hid;
    bias[nt] = bih[col] + bhh[col];
    #pragma unroll
    for (int kt = 0; kt < 4; ++kt) {
      const int k0 = kt * 32 + quad * 8;
      const float* pih = wih + col * C + k0;
      const float* phh = whh + col * C + k0;
      short8 a, b;
      #pragma unroll
      for (int j = 0; j < 8; ++j) {
        a[j] = (short)f2bf(pih[j]);
        b[j] = (short)f2bf(phh[j]);
      }
      fih[nt][kt] = a;
      fhh[nt][kt] = b;
    }
  }

  // ---- x staging: thread covers channel xc, samples xn..xn+3 (float4) ----
  const int xc = tid >> 2;          // 0..127
  const int xn = (tid & 3) * 4;     // 0,4,8,12
  const float* xptr = img + (size_t)xc * NPIX + n0 + xn;
  {
    float4 v = *(const float4*)xptr;   // x_0
    xs[0][(xn + 0) * LS + xc] = f2bf(v.x);
    xs[0][(xn + 1) * LS + xc] = f2bf(v.y);
    xs[0][(xn + 2) * LS + xc] = f2bf(v.z);
    xs[0][(xn + 3) * LS + xc] = f2bf(v.w);
  }
  for (int i = tid; i < 16 * LS; i += 512) hs[0][i] = 0;
  __syncthreads();

  float cc[4] = {0.f, 0.f, 0.f, 0.f};
  float hv[4];
  const int fro = l15 * LS + quad * 8;

  float* ob = out + (size_t)(n0 + quad * 4) * (TT * H) + hid;
  const size_t ostep = (size_t)TT * H;       // row stride between samples
  const float* xpf = xptr + (size_t)C * NPIX;  // points at x_{t+1}

  // ================= driven phase =================
  for (int t = 0; t < T; ++t) {
    const int rb = t & 1, wb = rb ^ 1;

    // store h(t-1): issued right after the barrier -> drains during compute
    if (t > 0) {
      #pragma unroll
      for (int r = 0; r < 4; ++r)
        __builtin_nontemporal_store(hv[r], ob + (size_t)r * ostep);
      ob += H;
    }

    // prefetch x_{t+1}
    const bool pf = (t + 1 < T);
    float4 q;
    if (pf) { q = *(const float4*)xpf; xpf += (size_t)C * NPIX; }

    f32x4 acc[4];
    #pragma unroll
    for (int nt = 0; nt < 4; ++nt)
      acc[nt] = (f32x4){bias[nt], bias[nt], bias[nt], bias[nt]};

    #pragma unroll
    for (int kt = 0; kt < 4; ++kt) {
      short8 ax = *(const short8*)&xs[rb][fro + kt * 32];
      short8 ah = *(const short8*)&hs[rb][fro + kt * 32];
      #pragma unroll
      for (int nt = 0; nt < 4; ++nt) {
        acc[nt] = __builtin_amdgcn_mfma_f32_16x16x32_bf16(ax, fih[nt][kt], acc[nt], 0, 0, 0);
        acc[nt] = __builtin_amdgcn_mfma_f32_16x16x32_bf16(ah, fhh[nt][kt], acc[nt], 0, 0, 0);
      }
    }

    #pragma unroll
    for (int r = 0; r < 4; ++r) {
      float ig = fast_sigmoid(acc[0][r]);
      float fg = fast_sigmoid(acc[1][r]);
      float gg = fast_tanh(acc[2][r]);
      float og = fast_sigmoid(acc[3][r]);
      cc[r] = fg * cc[r] + ig * gg;
      hv[r] = og * fast_tanh(cc[r]);
    }

    #pragma unroll
    for (int r = 0; r < 4; ++r)
      hs[wb][(quad * 4 + r) * LS + hid] = f2bf(hv[r]);
    if (pf) {
      xs[wb][(xn + 0) * LS + xc] = f2bf(q.x);
      xs[wb][(xn + 1) * LS + xc] = f2bf(q.y);
      xs[wb][(xn + 2) * LS + xc] = f2bf(q.z);
      xs[wb][(xn + 3) * LS + xc] = f2bf(q.w);
    }
    __syncthreads();
  }

  // ---- fold W_sum = W_ih + W_hh for the AR phase (registers only) ----
  #pragma unroll
  for (int nt = 0; nt < 4; ++nt)
    #pragma unroll
    for (int kt = 0; kt < 4; ++kt) {
      short8 a = fih[nt][kt], b = fhh[nt][kt];
      #pragma unroll
      for (int j = 0; j < 8; ++j)
        a[j] = (short)f2bf(bf2f((unsigned short)a[j]) + bf2f((unsigned short)b[j]));
      fih[nt][kt] = a;
    }

  // ================= autoregressive phase =================
  for (int t = T; t < TT; ++t) {
    const int rb = t & 1, wb = rb ^ 1;

    #pragma unroll
    for (int r = 0; r < 4; ++r)
      __builtin_nontemporal_store(hv[r], ob + (size_t)r * ostep);
    ob += H;

    f32x4 acc[4];
    #pragma unroll
    for (int nt = 0; nt < 4; ++nt)
      acc[nt] = (f32x4){bias[nt], bias[nt], bias[nt], bias[nt]};

    #pragma unroll
    for (int kt = 0; kt < 4; ++kt) {
      short8 ah = *(const short8*)&hs[rb][fro + kt * 32];
      #pragma unroll
      for (int nt = 0; nt < 4; ++nt)
        acc[nt] = __builtin_amdgcn_mfma_f32_16x16x32_bf16(ah, fih[nt][kt], acc[nt], 0, 0, 0);
    }

    #pragma unroll
    for (int r = 0; r < 4; ++r) {
      float ig = fast_sigmoid(acc[0][r]);
      float fg = fast_sigmoid(acc[1][r]);
      float gg = fast_tanh(acc[2][r]);
      float og = fast_sigmoid(acc[3][r]);
      cc[r] = fg * cc[r] + ig * gg;
      hv[r] = og * fast_tanh(cc[r]);
    }

    #pragma unroll
    for (int r = 0; r < 4; ++r)
      hs[wb][(quad * 4 + r) * LS + hid] = f2bf(hv[r]);
    __syncthreads();
  }

  // final output row
  #pragma unroll
  for (int r = 0; r < 4; ++r)
    __builtin_nontemporal_store(hv[r], ob + (size_t)r * ostep);
}

extern "C" void kernel_launch(void* const* d_in, const int* in_sizes, int n_in,
                              void* d_out, int out_size, void* d_ws, size_t ws_size,
                              hipStream_t stream) {
  (void)in_sizes; (void)n_in; (void)d_ws; (void)ws_size; (void)out_size;
  const float* img = (const float*)d_in[0];
  // d_in[1] = mask (unused by reference forward)
  const float* wih = (const float*)d_in[2];
  const float* whh = (const float*)d_in[3];
  const float* bih = (const float*)d_in[4];
  const float* bhh = (const float*)d_in[5];
  // d_in[6] = gp_affected_timesteps (static = 5, baked into EXTRA/TT)
  float* out = (float*)d_out;

  lstm_persistent<<<NPIX / 16, 512, 0, stream>>>(img, wih, whh, bih, bhh, out);
}